// Round 1
// baseline (157.096 us; speedup 1.0000x reference)
//
#include <hip/hip_runtime.h>

// Deformable conv (K=3, stride=1, pad=1, dil=1), N=8, Cin=Cout=128, H=W=64.
// v2: - prep_all merges weight-convert + x-transpose (one launch fewer);
//       prep_x phase-1 now float4 loads into a rotate-swizzled tile (2-way read conflicts only).
//     - deform_main: wts LDS tile REMOVED; B-fragments load straight from L2/L1-hot wt
//       into VGPRs (two 8-frag groups, issued before sampling / before barrier).
//       samp double-buffered -> ONE barrier per kk (9 vs 18 full drains).
// ws usage: xt = 8 MB at ws+0, wt = 288 KB at ws+8388608. Fully rewritten each launch.

#define H  64
#define W  64
#define CIN 128
#define COUT 128
#define NB 8
#define KK 9

typedef short bf16x8 __attribute__((ext_vector_type(8)));
typedef float f32x4  __attribute__((ext_vector_type(4)));

__device__ __forceinline__ unsigned short f2bf(float f) {
    unsigned u = __builtin_bit_cast(unsigned, f);
    u += 0x7FFFu + ((u >> 16) & 1u);          // round-nearest-even
    return (unsigned short)(u >> 16);
}
__device__ __forceinline__ float lo_f(unsigned u) { return __builtin_bit_cast(float, u << 16); }
__device__ __forceinline__ float hi_f(unsigned u) { return __builtin_bit_cast(float, u & 0xFFFF0000u); }

// Merged prep: blocks [0, NB*H) transpose x (NCHW fp32 -> NHWC bf16);
// blocks [NB*H, NB*H+576) convert weight fp32 [co][c][kk] -> bf16 [kk][co][c].
__global__ void prep_all(const float* __restrict__ x, const float* __restrict__ w,
                         unsigned short* __restrict__ xt, unsigned short* __restrict__ wt) {
    int b = blockIdx.x;
    int t = threadIdx.x;
    if (b >= NB * H) {                        // ---- weight part ----
        int idx = (b - NB * H) * 256 + t;
        if (idx < KK * COUT * CIN) {
            int kk = idx / (COUT * CIN);
            int r  = idx - kk * (COUT * CIN);
            int co = r >> 7;
            int c  = r & 127;
            wt[idx] = f2bf(w[(co * CIN + c) * KK + kk]);
        }
        return;
    }
    // ---- x-transpose part: one (n,y) row per block ----
    // tile stride 68 floats (== 4 mod 32 banks); logical col x stored at
    // physical (x + 16*(c>>5)) & 63  -> phase-2 scalar reads are 2-way (free).
    __shared__ float tile[CIN][W + 4];
    int n = b >> 6, y = b & 63;
    const float* src = x + ((size_t)n * CIN * H + y) * W;
    #pragma unroll
    for (int it = 0; it < 8; ++it) {
        int idx = it * 256 + t;               // 0..2047 float4s
        int c  = idx >> 4;
        int x4 = (idx & 15) << 2;
        int xs = (x4 + ((c >> 5) << 4)) & 63;
        *(float4*)&tile[c][xs] = *(const float4*)(src + (size_t)c * H * W + x4);
    }
    __syncthreads();
    int xp = t >> 2;                          // x position 0..63 (per wave: 16)
    int cbch = (t & 3) << 5;                  // channel base (32-ch chunk)
    int xr = (xp + ((cbch >> 5) << 4)) & 63;  // c>>5 constant within chunk
    unsigned short* dst = xt + (((size_t)(n * H + y) * W + xp) * CIN + cbch);
    unsigned rr[16];
    #pragma unroll
    for (int i = 0; i < 16; ++i) {
        float v0 = tile[cbch + 2 * i][xr];
        float v1 = tile[cbch + 2 * i + 1][xr];
        rr[i] = (unsigned)f2bf(v0) | ((unsigned)f2bf(v1) << 16);
    }
    #pragma unroll
    for (int i = 0; i < 4; ++i)
        ((uint4*)dst)[i] = make_uint4(rr[4*i], rr[4*i+1], rr[4*i+2], rr[4*i+3]);
}

// One block per (n, ho). 512 threads = 8 waves.
// Wave w: positions (w>>1)*16..+15 (wo), couts (w&1)*64..+63 (4 n-tiles of 16).
// B-fragments come straight from global wt (L1/L2-hot, 32KB per kk slice);
// samp double-buffered -> one barrier per kk.
__global__ __launch_bounds__(512, 4) void deform_main(
        const float* __restrict__ offs, const unsigned short* __restrict__ xt,
        const unsigned short* __restrict__ wt, float* __restrict__ out) {
    // +8 bf16 pad per row: 16B-aligned b128 reads, row stride == 4 mod 32 banks (free)
    __shared__ __attribute__((aligned(16))) unsigned short samp[2][64][CIN + 8];

    int b = blockIdx.x;
    int n = b >> 6, ho = b & 63;
    int t = threadIdx.x;
    int lane = t & 63, wv = t >> 6;
    int lm = lane & 15, lq = lane >> 4;
    int prow = ((wv >> 1) << 4) + lm;       // sampled-row (== wo) for A frag, m = lane&15
    int cobase = (wv & 1) << 6;

    f32x4 acc[4] = {{0,0,0,0},{0,0,0,0},{0,0,0,0},{0,0,0,0}};

    // sampling work split: thread -> (position p, 16-channel chunk cb)
    int p  = t >> 3;                        // wo 0..63
    int cb = (t & 7) << 4;                  // channel base
    const float* offbase = offs + (((size_t)n * 2 * KK) * H + ho) * W + p;
    const unsigned short* xrow = xt + (size_t)n * H * W * CIN + cb;
    // per-thread B-fragment base: frag(kk,nt,ct) at
    //   wt[(kk*COUT + cobase + nt*16 + lm)*CIN + ct*32 + lq*8]
    const unsigned short* wfb = wt + (((size_t)(cobase + lm)) << 7) + (lq << 3);

    for (int kk = 0; kk < KK; ++kk) {
        const unsigned short* wk = wfb + ((size_t)kk << 14);   // kk*COUT*CIN
        bf16x8 b01[2][4], b23[2][4];
        // group 1: ct 0..1 — issued before sampling, latency hides under gathers
        #pragma unroll
        for (int ct = 0; ct < 2; ++ct)
            #pragma unroll
            for (int nt = 0; nt < 4; ++nt)
                b01[ct][nt] = *(const bf16x8*)(wk + (nt << 11) + (ct << 5));

        // ---- bilinear-sample 16 channels for position p into samp[kk&1][p][cb..] ----
        {
            float dy = offbase[(size_t)(2 * kk) * H * W];
            float dx = offbase[(size_t)(2 * kk + 1) * H * W];
            float py = (float)(ho - 1 + kk / 3) + dy;
            float px = (float)(p  - 1 + kk % 3) + dx;
            float y0f = floorf(py), x0f = floorf(px);
            float wy1 = py - y0f, wx1 = px - x0f;
            float wy0 = 1.f - wy1, wx0 = 1.f - wx1;
            int y0 = (int)y0f, x0 = (int)x0f;
            int y1 = y0 + 1, x1 = x0 + 1;
            bool vy0 = (unsigned)y0 < (unsigned)H, vy1 = (unsigned)y1 < (unsigned)H;
            bool vx0 = (unsigned)x0 < (unsigned)W, vx1 = (unsigned)x1 < (unsigned)W;
            float w00 = (vy0 && vx0) ? wy0 * wx0 : 0.f;
            float w01 = (vy0 && vx1) ? wy0 * wx1 : 0.f;
            float w10 = (vy1 && vx0) ? wy1 * wx0 : 0.f;
            float w11 = (vy1 && vx1) ? wy1 * wx1 : 0.f;
            int yc0 = min(max(y0, 0), H - 1), yc1 = min(max(y1, 0), H - 1);
            int xc0 = min(max(x0, 0), W - 1), xc1 = min(max(x1, 0), W - 1);
            const unsigned short* r0 = xrow + (size_t)yc0 * W * CIN;
            const unsigned short* r1 = xrow + (size_t)yc1 * W * CIN;
            const unsigned short* c00 = r0 + xc0 * CIN;
            const unsigned short* c01 = r0 + xc1 * CIN;
            const unsigned short* c10 = r1 + xc0 * CIN;
            const unsigned short* c11 = r1 + xc1 * CIN;
            #pragma unroll
            for (int j = 0; j < 2; ++j) {
                uint4 q00 = *(const uint4*)(c00 + 8 * j);
                uint4 q01 = *(const uint4*)(c01 + 8 * j);
                uint4 q10 = *(const uint4*)(c10 + 8 * j);
                uint4 q11 = *(const uint4*)(c11 + 8 * j);
                const unsigned* a0 = (const unsigned*)&q00;
                const unsigned* a1 = (const unsigned*)&q01;
                const unsigned* a2 = (const unsigned*)&q10;
                const unsigned* a3 = (const unsigned*)&q11;
                unsigned rr[4];
                #pragma unroll
                for (int i = 0; i < 4; ++i) {
                    float v0 = w00*lo_f(a0[i]) + w01*lo_f(a1[i]) + w10*lo_f(a2[i]) + w11*lo_f(a3[i]);
                    float v1 = w00*hi_f(a0[i]) + w01*hi_f(a1[i]) + w10*hi_f(a2[i]) + w11*hi_f(a3[i]);
                    rr[i] = (unsigned)f2bf(v0) | ((unsigned)f2bf(v1) << 16);
                }
                *(uint4*)&samp[kk & 1][p][cb + 8 * j] = make_uint4(rr[0], rr[1], rr[2], rr[3]);
            }
        }
        // group 2: ct 2..3 — issued before the barrier, waited at MFMA use
        #pragma unroll
        for (int ct = 0; ct < 2; ++ct)
            #pragma unroll
            for (int nt = 0; nt < 4; ++nt)
                b23[ct][nt] = *(const bf16x8*)(wk + (nt << 11) + ((ct + 2) << 5));

        __syncthreads();      // samp[kk&1] ready; also orders reuse of this buffer at kk+2

        // ---- MFMA: A = samp (m=pos), B = reg fragments (n=cout), K-chunk = 128 ch ----
        #pragma unroll
        for (int ct = 0; ct < 4; ++ct) {
            bf16x8 a = *(const bf16x8*)&samp[kk & 1][prow][(ct << 5) + (lq << 3)];
            #pragma unroll
            for (int nt = 0; nt < 4; ++nt) {
                bf16x8 bq = (ct == 0) ? b01[0][nt]
                          : (ct == 1) ? b01[1][nt]
                          : (ct == 2) ? b23[0][nt]
                          :             b23[1][nt];
                acc[nt] = __builtin_amdgcn_mfma_f32_16x16x32_bf16(a, bq, acc[nt], 0, 0, 0);
            }
        }
        // no trailing barrier: next kk writes the other samp buffer; the kk+1
        // barrier orders everyone's kk MFMA reads before kk+2's overwrite.
    }
    // epilogue: D[m=4*lq+r][n=lane&15] -> out[n][co][ho][wo], 4 consecutive wo = float4
    int wo = ((wv >> 1) << 4) + (lq << 2);
    #pragma unroll
    for (int nt = 0; nt < 4; ++nt) {
        int co = cobase + (nt << 4) + lm;
        *(f32x4*)(out + (((size_t)(n * COUT + co) * H + ho) * W + wo)) = acc[nt];
    }
}

extern "C" void kernel_launch(void* const* d_in, const int* in_sizes, int n_in,
                              void* d_out, int out_size, void* d_ws, size_t ws_size,
                              hipStream_t stream) {
    const float* x      = (const float*)d_in[0];   // (8,128,64,64)
    const float* offset = (const float*)d_in[1];   // (8,18,64,64)
    const float* weight = (const float*)d_in[2];   // (128,128,3,3)
    float* out = (float*)d_out;

    unsigned short* xt = (unsigned short*)d_ws;                                  // 8 MB
    unsigned short* wt = (unsigned short*)((char*)d_ws + (size_t)NB*H*W*CIN*2);  // 288 KB

    int wblocks = (KK * COUT * CIN + 255) / 256;   // 576
    hipLaunchKernelGGL(prep_all, dim3(NB * H + wblocks), dim3(256), 0, stream,
                       x, weight, xt, wt);
    hipLaunchKernelGGL(deform_main, dim3(NB * H), dim3(512), 0, stream,
                       offset, xt, wt, out);
}

// Round 2
// 110.355 us; speedup vs baseline: 1.4235x; 1.4235x over previous
//
#include <hip/hip_runtime.h>

// Deformable conv (K=3, stride=1, pad=1, dil=1), N=8, Cin=Cout=128, H=W=64.
// v3: - blocks cover TWO output rows (grid 256, 512 thr = 8 waves);
//       wave tile 64 pos x 32 cout via verified 16x16x32 bf16 MFMA (4 m-subtiles x 2 n-subtiles)
//       -> LDS-read bytes/lane/kk drop 1.67x vs v1 (384B per 2048-area vs 320B per 1024-area).
//     - samp AND wts double-buffered (139KB LDS, 1 block/CU) -> ONE barrier per kk.
//     - software pipeline: issue kk+1 gathers + weight loads into regs (offsets prefetched
//       kk+2) BEFORE MFMA(kk); wait+blend+LDS-write after MFMA; vmcnt drains before the
//       barrier (race-free). sched_barrier(0) pins the load issue above the MFMAs
//       (round-1 lesson: compiler sinks global loads to uses otherwise).
// ws usage: xt = 8 MB at ws+0, wt = 288 KB at ws+8388608. Fully rewritten each launch.

#define H  64
#define W  64
#define CIN 128
#define COUT 128
#define NB 8
#define KK 9

typedef short bf16x8 __attribute__((ext_vector_type(8)));
typedef float f32x4  __attribute__((ext_vector_type(4)));

__device__ __forceinline__ unsigned short f2bf(float f) {
    unsigned u = __builtin_bit_cast(unsigned, f);
    u += 0x7FFFu + ((u >> 16) & 1u);          // round-nearest-even
    return (unsigned short)(u >> 16);
}
__device__ __forceinline__ float lo_f(unsigned u) { return __builtin_bit_cast(float, u << 16); }
__device__ __forceinline__ float hi_f(unsigned u) { return __builtin_bit_cast(float, u & 0xFFFF0000u); }

// Merged prep: blocks [0, NB*H) transpose x (NCHW fp32 -> NHWC bf16);
// blocks [NB*H, NB*H+576) convert weight fp32 [co][c][kk] -> bf16 [kk][co][c].
__global__ void prep_all(const float* __restrict__ x, const float* __restrict__ w,
                         unsigned short* __restrict__ xt, unsigned short* __restrict__ wt) {
    int b = blockIdx.x;
    int t = threadIdx.x;
    if (b >= NB * H) {                        // ---- weight part ----
        int idx = (b - NB * H) * 256 + t;
        if (idx < KK * COUT * CIN) {
            int kk = idx / (COUT * CIN);
            int r  = idx - kk * (COUT * CIN);
            int co = r >> 7;
            int c  = r & 127;
            wt[idx] = f2bf(w[(co * CIN + c) * KK + kk]);
        }
        return;
    }
    // ---- x-transpose part: one (n,y) row per block ----
    __shared__ float tile[CIN][W + 4];
    int n = b >> 6, y = b & 63;
    const float* src = x + ((size_t)n * CIN * H + y) * W;
    #pragma unroll
    for (int it = 0; it < 8; ++it) {
        int idx = it * 256 + t;               // 0..2047 float4s
        int c  = idx >> 4;
        int x4 = (idx & 15) << 2;
        int xs = (x4 + ((c >> 5) << 4)) & 63; // rotate-swizzle per 32-ch group
        *(float4*)&tile[c][xs] = *(const float4*)(src + (size_t)c * H * W + x4);
    }
    __syncthreads();
    int xp = t >> 2;                          // x position 0..63
    int cbch = (t & 3) << 5;                  // channel base (32-ch chunk)
    int xr = (xp + ((cbch >> 5) << 4)) & 63;
    unsigned short* dst = xt + (((size_t)(n * H + y) * W + xp) * CIN + cbch);
    unsigned rr[16];
    #pragma unroll
    for (int i = 0; i < 16; ++i) {
        float v0 = tile[cbch + 2 * i][xr];
        float v1 = tile[cbch + 2 * i + 1][xr];
        rr[i] = (unsigned)f2bf(v0) | ((unsigned)f2bf(v1) << 16);
    }
    #pragma unroll
    for (int i = 0; i < 4; ++i)
        ((uint4*)dst)[i] = make_uint4(rr[4*i], rr[4*i+1], rr[4*i+2], rr[4*i+3]);
}

struct GatherCtx {
    const unsigned short *c00, *c01, *c10, *c11;
    float w00, w01, w10, w11;
};

__device__ __forceinline__ GatherCtx gather_setup(float dy, float dx, int ho, int wo, int kk,
                                                  const unsigned short* xbase) {
    GatherCtx g;
    float py = (float)(ho - 1 + kk / 3) + dy;
    float px = (float)(wo - 1 + kk % 3) + dx;
    float y0f = floorf(py), x0f = floorf(px);
    float wy1 = py - y0f, wx1 = px - x0f;
    float wy0 = 1.f - wy1, wx0 = 1.f - wx1;
    int y0 = (int)y0f, x0 = (int)x0f;
    int y1 = y0 + 1, x1 = x0 + 1;
    bool vy0 = (unsigned)y0 < (unsigned)H, vy1 = (unsigned)y1 < (unsigned)H;
    bool vx0 = (unsigned)x0 < (unsigned)W, vx1 = (unsigned)x1 < (unsigned)W;
    g.w00 = (vy0 && vx0) ? wy0 * wx0 : 0.f;
    g.w01 = (vy0 && vx1) ? wy0 * wx1 : 0.f;
    g.w10 = (vy1 && vx0) ? wy1 * wx0 : 0.f;
    g.w11 = (vy1 && vx1) ? wy1 * wx1 : 0.f;
    int yc0 = min(max(y0, 0), H - 1), yc1 = min(max(y1, 0), H - 1);
    int xc0 = min(max(x0, 0), W - 1), xc1 = min(max(x1, 0), W - 1);
    const unsigned short* r0 = xbase + (size_t)yc0 * W * CIN;
    const unsigned short* r1 = xbase + (size_t)yc1 * W * CIN;
    g.c00 = r0 + xc0 * CIN;  g.c01 = r0 + xc1 * CIN;
    g.c10 = r1 + xc0 * CIN;  g.c11 = r1 + xc1 * CIN;
    return g;
}

__device__ __forceinline__ void gather_issue(const GatherCtx& g, uint4* gv) {
    #pragma unroll
    for (int j = 0; j < 4; ++j) {            // 4 x 8-channel chunks = 32 ch/thread
        gv[4*j+0] = *(const uint4*)(g.c00 + 8*j);
        gv[4*j+1] = *(const uint4*)(g.c01 + 8*j);
        gv[4*j+2] = *(const uint4*)(g.c10 + 8*j);
        gv[4*j+3] = *(const uint4*)(g.c11 + 8*j);
    }
}

__device__ __forceinline__ void gather_blend_store(const GatherCtx& g, const uint4* gv,
                                                   unsigned short* dst) {
    #pragma unroll
    for (int j = 0; j < 4; ++j) {
        const unsigned* a0 = (const unsigned*)&gv[4*j+0];
        const unsigned* a1 = (const unsigned*)&gv[4*j+1];
        const unsigned* a2 = (const unsigned*)&gv[4*j+2];
        const unsigned* a3 = (const unsigned*)&gv[4*j+3];
        unsigned rr[4];
        #pragma unroll
        for (int i = 0; i < 4; ++i) {
            float v0 = g.w00*lo_f(a0[i]) + g.w01*lo_f(a1[i]) + g.w10*lo_f(a2[i]) + g.w11*lo_f(a3[i]);
            float v1 = g.w00*hi_f(a0[i]) + g.w01*hi_f(a1[i]) + g.w10*hi_f(a2[i]) + g.w11*hi_f(a3[i]);
            rr[i] = (unsigned)f2bf(v0) | ((unsigned)f2bf(v1) << 16);
        }
        *(uint4*)(dst + 8*j) = make_uint4(rr[0], rr[1], rr[2], rr[3]);
    }
}

// One block per (n, ho-pair). 512 threads = 8 waves.
// Wave w: row r = w&1 (ho = 2*ho2+r), co tile (w>>1)*32. Wave output = 64 wo x 32 co.
__global__ __launch_bounds__(512, 2) void deform_main(
        const float* __restrict__ offs, const unsigned short* __restrict__ xt,
        const unsigned short* __restrict__ wt, float* __restrict__ out) {
    // +8 bf16 pad per row -> row stride 272B (68 words == 4 mod 32 banks): conflict-free b128
    __shared__ __attribute__((aligned(16))) unsigned short samp[2][128][CIN + 8];  // 69,632 B
    __shared__ __attribute__((aligned(16))) unsigned short wts [2][COUT][CIN + 8]; // 69,632 B

    int b = blockIdx.x;
    int n = b >> 5, ho2 = b & 31;
    int t = threadIdx.x;
    int lane = t & 63, wv = t >> 6;
    int lm = lane & 15, lq = lane >> 4;
    int rw = wv & 1;                        // row within the ho-pair
    int cobase = (wv >> 1) << 5;            // 0,32,64,96
    int arow = (rw << 6) + lm;              // samp row base for A frags

    f32x4 acc[4][2];
    #pragma unroll
    for (int mt = 0; mt < 4; ++mt)
        #pragma unroll
        for (int nt = 0; nt < 2; ++nt) acc[mt][nt] = f32x4{0.f, 0.f, 0.f, 0.f};

    // sampling map: thread -> (position p in 0..127, 32-channel chunk cb)
    int p  = t >> 2;
    int cb = (t & 3) << 5;
    int ho = (ho2 << 1) + (p >> 6);
    int wo = p & 63;
    const float* offbase = offs + (size_t)n * 2 * KK * H * W + (size_t)ho * W + wo;
    const unsigned short* xbase = xt + (size_t)n * H * W * CIN + cb;
    unsigned short* sdst0 = &samp[0][p][cb];
    unsigned short* sdst1 = &samp[1][p][cb];

    // weight staging map: thread -> (cout row sco, 32-channel chunk sch); 64B/thread/kk
    int sco = t >> 2;
    int sch = (t & 3) << 5;
    const unsigned short* wsrc = wt + (size_t)sco * CIN + sch;
    unsigned short* wdst0 = &wts[0][sco][sch];
    unsigned short* wdst1 = &wts[1][sco][sch];

    // ---- prologue: stage kk=0 into buf0; prefetch offsets for kk=1 ----
    float dyA, dxA;
    {
        float dy0 = offbase[0];
        float dx0 = offbase[(size_t)H * W];
        uint4 wg[4];
        #pragma unroll
        for (int i = 0; i < 4; ++i) wg[i] = *(const uint4*)(wsrc + (i << 3));
        GatherCtx g = gather_setup(dy0, dx0, ho, wo, 0, xbase);
        uint4 gv[16];
        gather_issue(g, gv);
        dyA = offbase[(size_t)(2) * H * W];
        dxA = offbase[(size_t)(3) * H * W];
        gather_blend_store(g, gv, sdst0);
        #pragma unroll
        for (int i = 0; i < 4; ++i) *(uint4*)(wdst0 + (i << 3)) = wg[i];
        __syncthreads();
    }

    for (int kk = 0; kk < KK; ++kk) {
        unsigned short (*sbuf)[CIN + 8] = samp[kk & 1];
        unsigned short (*wbuf)[CIN + 8] = wts[kk & 1];
        GatherCtx g;
        uint4 gv[16], wg[4];
        bool pre = (kk < KK - 1);
        if (pre) {
            // issue next-kk loads; offsets already in regs (prefetched last iter)
            g = gather_setup(dyA, dxA, ho, wo, kk + 1, xbase);
            gather_issue(g, gv);
            const unsigned short* wk = wsrc + ((size_t)(kk + 1) << 14);  // (kk+1)*COUT*CIN
            #pragma unroll
            for (int i = 0; i < 4; ++i) wg[i] = *(const uint4*)(wk + (i << 3));
            if (kk < KK - 2) {
                dyA = offbase[(size_t)(2 * (kk + 2)) * H * W];
                dxA = offbase[(size_t)(2 * (kk + 2) + 1) * H * W];
            }
        }
        __builtin_amdgcn_sched_barrier(0);   // keep the load issue above the MFMAs

        // ---- MFMA(kk): A = samp rows (m=wo), B^T = wts rows (n=co), K = 128 ch ----
        #pragma unroll
        for (int ct = 0; ct < 4; ++ct) {
            bf16x8 a[4];
            #pragma unroll
            for (int mt = 0; mt < 4; ++mt)
                a[mt] = *(const bf16x8*)&sbuf[arow + (mt << 4)][(ct << 5) + (lq << 3)];
            bf16x8 bb[2];
            #pragma unroll
            for (int nt = 0; nt < 2; ++nt)
                bb[nt] = *(const bf16x8*)&wbuf[cobase + (nt << 4) + lm][(ct << 5) + (lq << 3)];
            #pragma unroll
            for (int mt = 0; mt < 4; ++mt)
                #pragma unroll
                for (int nt = 0; nt < 2; ++nt)
                    acc[mt][nt] = __builtin_amdgcn_mfma_f32_16x16x32_bf16(a[mt], bb[nt], acc[mt][nt], 0, 0, 0);
        }

        if (pre) {
            // loads have had the whole MFMA phase to land; drain, blend, write next buf
            unsigned short* sd = (kk & 1) ? sdst0 : sdst1;
            unsigned short* wd = (kk & 1) ? wdst0 : wdst1;
            gather_blend_store(g, gv, sd);
            #pragma unroll
            for (int i = 0; i < 4; ++i) *(uint4*)(wd + (i << 3)) = wg[i];
        }
        __syncthreads();   // next buf ready; also orders this buf's reuse at kk+2
    }

    // epilogue: D[m = mt*16 + lq*4 + j][n = lm] -> out[n][co][ho][wo], float4 over wo
    int hoo = (ho2 << 1) + rw;
    #pragma unroll
    for (int mt = 0; mt < 4; ++mt) {
        int wob = (mt << 4) + (lq << 2);
        #pragma unroll
        for (int nt = 0; nt < 2; ++nt) {
            int co = cobase + (nt << 4) + lm;
            *(f32x4*)(out + (((size_t)(n * COUT + co) * H + hoo) * W + wob)) = acc[mt][nt];
        }
    }
}

extern "C" void kernel_launch(void* const* d_in, const int* in_sizes, int n_in,
                              void* d_out, int out_size, void* d_ws, size_t ws_size,
                              hipStream_t stream) {
    const float* x      = (const float*)d_in[0];   // (8,128,64,64)
    const float* offset = (const float*)d_in[1];   // (8,18,64,64)
    const float* weight = (const float*)d_in[2];   // (128,128,3,3)
    float* out = (float*)d_out;

    unsigned short* xt = (unsigned short*)d_ws;                                  // 8 MB
    unsigned short* wt = (unsigned short*)((char*)d_ws + (size_t)NB*H*W*CIN*2);  // 288 KB

    int wblocks = (KK * COUT * CIN + 255) / 256;   // 576
    hipLaunchKernelGGL(prep_all, dim3(NB * H + wblocks), dim3(256), 0, stream,
                       x, weight, xt, wt);
    hipLaunchKernelGGL(deform_main, dim3(NB * H / 2), dim3(512), 0, stream,
                       offset, xt, wt, out);
}